// Round 7
// baseline (156.502 us; speedup 1.0000x reference)
//
#include <hip/hip_runtime.h>

// SVD_Solver: weighted Kabsch per (batch, joint).  B=4096, M=64, J=24.
// Round 7: R6 structure (joint-quad per thread -> 4x fewer VMEM instrs) with
// the UB fixed: R6 read 12 floats through &oa.x across three separate float4
// locals (indices 4..11 = garbage). Now each float4 is splatted component-wise
// into a real local array (register renames, zero extra instrs).

constexpr int M = 64;
constexpr int J = 24;
constexpr int NQ = J / 4;         // 6 joint-quads per batch
constexpr int KSP = 8;            // in-wave m-split (lane bits 3..5)
constexpr int QPW = 8;            // quads per wave (lane bits 0..2)
constexpr int QPB = 32;           // quads per 256-thread block

// ---- accum: thread (quad q4, k) sums m = k*8 .. k*8+7 for 4 joints ----
__global__ __launch_bounds__(256, 3) void accum_kernel(
    const float* __restrict__ points,   // (B, 64, 3)
    const float* __restrict__ weight,   // (B, 64, 24)
    const float* __restrict__ offset,   // (B, 64, 24, 3)
    float* __restrict__ ws,             // AoS: 16 floats per solve
    int q4_total, int bj_total)
{
    const int t    = threadIdx.x;
    const int lane = t & 63;
    const int wv   = t >> 6;
    const int k    = lane >> 3;         // m-split 0..7
    const int sl   = lane & 7;          // quad-in-wave (memory-consecutive)
    const int q4   = blockIdx.x * QPB + wv * QPW + sl;
    const int q4c  = q4 < q4_total ? q4 : q4_total - 1;
    const int b    = q4c / NQ;
    const int jg   = q4c - b * NQ;      // joint-quad 0..5
    const int j0   = jg * 4;

    // f4 bases (alignment: j0*4B and j0*12B are 16B multiples)
    const float4* wq = (const float4*)(weight + (size_t)b * (M * J) + (size_t)(k * 8) * J + j0);
    const float4* oq = (const float4*)(offset + ((size_t)b * (M * J) + (size_t)(k * 8) * J + j0) * 3);
    const float*  pq = points + (size_t)b * (M * 3) + (size_t)(k * 8) * 3;

    // per-joint accs: [0]=W [1..3]=Wo [4..6]=Wp [7..9]=To [10..18]=S row-major
    float a[4][19];
    float tp[3] = {0.f, 0.f, 0.f};
#pragma unroll
    for (int jj = 0; jj < 4; ++jj)
#pragma unroll
        for (int n = 0; n < 19; ++n) a[jj][n] = 0.0f;

#pragma unroll
    for (int i = 0; i < M / KSP; ++i) {
        float4 wf = wq[i * (J / 4)];                       // stride 24 floats = 6 f4
        float4 oa = oq[i * (J * 3 / 4) + 0];               // stride 72 floats = 18 f4
        float4 ob = oq[i * (J * 3 / 4) + 1];
        float4 oc = oq[i * (J * 3 / 4) + 2];
        float p0 = pq[i * 3 + 0];
        float p1 = pq[i * 3 + 1];
        float p2 = pq[i * 3 + 2];
        tp[0] += p0; tp[1] += p1; tp[2] += p2;
        float of[12];                                      // proper register array
        of[0] = oa.x; of[1]  = oa.y; of[2]  = oa.z; of[3]  = oa.w;
        of[4] = ob.x; of[5]  = ob.y; of[6]  = ob.z; of[7]  = ob.w;
        of[8] = oc.x; of[9]  = oc.y; of[10] = oc.z; of[11] = oc.w;
        float wf4[4];
        wf4[0] = wf.x; wf4[1] = wf.y; wf4[2] = wf.z; wf4[3] = wf.w;
#pragma unroll
        for (int jj = 0; jj < 4; ++jj) {
            float w  = wf4[jj];
            float o0 = of[jj * 3 + 0];
            float o1 = of[jj * 3 + 1];
            float o2 = of[jj * 3 + 2];
            a[jj][0] += w;
            a[jj][1] = fmaf(w, o0, a[jj][1]);  a[jj][2] = fmaf(w, o1, a[jj][2]);  a[jj][3] = fmaf(w, o2, a[jj][3]);
            a[jj][4] = fmaf(w, p0, a[jj][4]);  a[jj][5] = fmaf(w, p1, a[jj][5]);  a[jj][6] = fmaf(w, p2, a[jj][6]);
            a[jj][7] += o0; a[jj][8] += o1; a[jj][9] += o2;
            a[jj][10] = fmaf(o0, p0, a[jj][10]); a[jj][11] = fmaf(o0, p1, a[jj][11]); a[jj][12] = fmaf(o0, p2, a[jj][12]);
            a[jj][13] = fmaf(o1, p0, a[jj][13]); a[jj][14] = fmaf(o1, p1, a[jj][14]); a[jj][15] = fmaf(o1, p2, a[jj][15]);
            a[jj][16] = fmaf(o2, p0, a[jj][16]); a[jj][17] = fmaf(o2, p1, a[jj][17]); a[jj][18] = fmaf(o2, p2, a[jj][18]);
        }
    }

    // butterfly-reduce over k (lane bits 3..5)
#pragma unroll
    for (int jj = 0; jj < 4; ++jj)
#pragma unroll
        for (int n = 0; n < 19; ++n) {
            float v = a[jj][n];
            v += __shfl_xor(v, 8);
            v += __shfl_xor(v, 16);
            v += __shfl_xor(v, 32);
            a[jj][n] = v;
        }
#pragma unroll
    for (int n = 0; n < 3; ++n) {
        float v = tp[n];
        v += __shfl_xor(v, 8);
        v += __shfl_xor(v, 16);
        v += __shfl_xor(v, 32);
        tp[n] = v;
    }

    if (k != 0 || q4 >= q4_total) return;

    const float fM = (float)M;
#pragma unroll
    for (int jj = 0; jj < 4; ++jj) {
        const float inv = __builtin_amdgcn_rcpf(a[jj][0]);
        const float cP0 = a[jj][1] * inv, cP1 = a[jj][2] * inv, cP2 = a[jj][3] * inv;
        const float cQ0 = a[jj][4] * inv, cQ1 = a[jj][5] * inv, cQ2 = a[jj][6] * inv;
        const float To0 = a[jj][7], To1 = a[jj][8], To2 = a[jj][9];
        float4 f0, f1, f2, f3;
        f0.x = a[jj][10] - cP0 * tp[0] - cQ0 * To0 + fM * cP0 * cQ0;
        f0.y = a[jj][11] - cP0 * tp[1] - cQ1 * To0 + fM * cP0 * cQ1;
        f0.z = a[jj][12] - cP0 * tp[2] - cQ2 * To0 + fM * cP0 * cQ2;
        f0.w = a[jj][13] - cP1 * tp[0] - cQ0 * To1 + fM * cP1 * cQ0;
        f1.x = a[jj][14] - cP1 * tp[1] - cQ1 * To1 + fM * cP1 * cQ1;
        f1.y = a[jj][15] - cP1 * tp[2] - cQ2 * To1 + fM * cP1 * cQ2;
        f1.z = a[jj][16] - cP2 * tp[0] - cQ0 * To2 + fM * cP2 * cQ0;
        f1.w = a[jj][17] - cP2 * tp[1] - cQ1 * To2 + fM * cP2 * cQ1;
        f2.x = a[jj][18] - cP2 * tp[2] - cQ2 * To2 + fM * cP2 * cQ2;
        f2.y = cP0; f2.z = cP1; f2.w = cP2;
        f3.x = cQ0; f3.y = cQ1; f3.z = cQ2; f3.w = 0.0f;
        const int bj = (b * NQ + jg) * 4 + jj;      // == b*24 + j0 + jj
        float4* dst = (float4*)(ws + (size_t)bj * 16);
        dst[0] = f0; dst[1] = f1; dst[2] = f2; dst[3] = f3;
    }
}

// ---- fast Jacobi rotation: single-instruction rcp/rsq/sqrt ----
template<int P, int Q>
__device__ __forceinline__ void jrot(float A[4][4], float V[4][4]) {
    float apq = A[P][Q];
    float theta = (A[Q][Q] - A[P][P]) * __builtin_amdgcn_rcpf(2.0f * apq);
    float t = __builtin_amdgcn_rcpf(fabsf(theta) + __builtin_amdgcn_sqrtf(fmaf(theta, theta, 1.0f)));
    t = (theta < 0.0f) ? -t : t;
    t = (apq == 0.0f) ? 0.0f : t;            // kills inf/NaN from rcp(0)
    float c = __builtin_amdgcn_rsqf(fmaf(t, t, 1.0f));
    float s = t * c;
#pragma unroll
    for (int k = 0; k < 4; ++k) {
        float akp = A[k][P], akq = A[k][Q];
        A[k][P] = c * akp - s * akq;
        A[k][Q] = s * akp + c * akq;
    }
#pragma unroll
    for (int k = 0; k < 4; ++k) {
        float apk = A[P][k], aqk = A[Q][k];
        A[P][k] = c * apk - s * aqk;
        A[Q][k] = s * apk + c * aqk;
        float vkp = V[k][P], vkq = V[k][Q];
        V[k][P] = c * vkp - s * vkq;
        V[k][Q] = s * vkp + c * vkq;
    }
}

__device__ __forceinline__ void horn_solve(
    float S00, float S01, float S02, float S10, float S11, float S12,
    float S20, float S21, float S22,
    float cP0, float cP1, float cP2, float cQ0, float cQ1, float cQ2,
    float* __restrict__ Rout, float* __restrict__ tout)
{
    float A[4][4], V[4][4];
    A[0][0] = S00 + S11 + S22;
    A[0][1] = A[1][0] = S12 - S21;
    A[0][2] = A[2][0] = S20 - S02;
    A[0][3] = A[3][0] = S01 - S10;
    A[1][1] = S00 - S11 - S22;
    A[1][2] = A[2][1] = S01 + S10;
    A[1][3] = A[3][1] = S02 + S20;
    A[2][2] = -S00 + S11 - S22;
    A[2][3] = A[3][2] = S12 + S21;
    A[3][3] = -S00 - S11 + S22;
#pragma unroll
    for (int r = 0; r < 4; ++r)
#pragma unroll
        for (int c = 0; c < 4; ++c)
            V[r][c] = (r == c) ? 1.0f : 0.0f;

#pragma unroll 1
    for (int sweep = 0; sweep < 6; ++sweep) {
        jrot<0, 1>(A, V); jrot<0, 2>(A, V); jrot<0, 3>(A, V);
        jrot<1, 2>(A, V); jrot<1, 3>(A, V); jrot<2, 3>(A, V);
    }

    float best = A[0][0];
    float qw = V[0][0], qx = V[1][0], qy = V[2][0], qz = V[3][0];
#pragma unroll
    for (int i = 1; i < 4; ++i) {
        bool better = A[i][i] > best;
        best = better ? A[i][i] : best;
        qw = better ? V[0][i] : qw;
        qx = better ? V[1][i] : qx;
        qy = better ? V[2][i] : qy;
        qz = better ? V[3][i] : qz;
    }
    float nrm = __builtin_amdgcn_rsqf(qw * qw + qx * qx + qy * qy + qz * qz);
    qw *= nrm; qx *= nrm; qy *= nrm; qz *= nrm;

    float R00 = 1.f - 2.f * (qy * qy + qz * qz);
    float R01 = 2.f * (qx * qy - qw * qz);
    float R02 = 2.f * (qx * qz + qw * qy);
    float R10 = 2.f * (qx * qy + qw * qz);
    float R11 = 1.f - 2.f * (qx * qx + qz * qz);
    float R12 = 2.f * (qy * qz - qw * qx);
    float R20 = 2.f * (qx * qz - qw * qy);
    float R21 = 2.f * (qy * qz + qw * qx);
    float R22 = 1.f - 2.f * (qx * qx + qy * qy);

    Rout[0] = R00; Rout[1] = R01; Rout[2] = R02;
    Rout[3] = R10; Rout[4] = R11; Rout[5] = R12;
    Rout[6] = R20; Rout[7] = R21; Rout[8] = R22;
    tout[0] = cQ0 - (R00 * cP0 + R01 * cP1 + R02 * cP2);
    tout[1] = cQ1 - (R10 * cP0 + R11 * cP1 + R12 * cP2);
    tout[2] = cQ2 - (R20 * cP0 + R21 * cP1 + R22 * cP2);
}

__global__ __launch_bounds__(256) void solve_kernel(
    const float* __restrict__ ws, float* __restrict__ out, int bj_total)
{
    int tid = blockIdx.x * 256 + threadIdx.x;
    if (tid >= bj_total) return;
    const float4* v = (const float4*)(ws + (size_t)tid * 16);
    float4 f0 = v[0], f1 = v[1], f2 = v[2], f3 = v[3];
    float Rr[9], tr[3];
    horn_solve(f0.x, f0.y, f0.z, f0.w, f1.x, f1.y, f1.z, f1.w, f2.x,
               f2.y, f2.z, f2.w, f3.x, f3.y, f3.z, Rr, tr);
    float* Rout = out + (size_t)tid * 9;
#pragma unroll
    for (int n = 0; n < 9; ++n) Rout[n] = Rr[n];
    float* tout = out + (size_t)bj_total * 9 + (size_t)tid * 3;
    tout[0] = tr[0]; tout[1] = tr[1]; tout[2] = tr[2];
}

// ---- fallback (ws too small): fused one-thread-per-solve ----
__global__ __launch_bounds__(256) void fused_kernel(
    const float* __restrict__ points, const float* __restrict__ weight,
    const float* __restrict__ offset, float* __restrict__ out, int bj_total)
{
    int tid = blockIdx.x * blockDim.x + threadIdx.x;
    if (tid >= bj_total) return;
    int b = tid / J, j = tid - b * J;
    const float* wq = weight + (size_t)b * M * J + j;
    const float* oq = offset + ((size_t)b * M * J + j) * 3;
    const float* pq = points + (size_t)b * M * 3;
    float a[22];
#pragma unroll
    for (int n = 0; n < 22; ++n) a[n] = 0.0f;
#pragma unroll 4
    for (int m = 0; m < M; ++m) {
        float w = wq[m * J];
        float o0 = oq[m * (J * 3) + 0], o1 = oq[m * (J * 3) + 1], o2 = oq[m * (J * 3) + 2];
        float p0 = pq[m * 3 + 0], p1 = pq[m * 3 + 1], p2 = pq[m * 3 + 2];
        a[0] += w;
        a[1] = fmaf(w, o0, a[1]); a[2] = fmaf(w, o1, a[2]); a[3] = fmaf(w, o2, a[3]);
        a[4] = fmaf(w, p0, a[4]); a[5] = fmaf(w, p1, a[5]); a[6] = fmaf(w, p2, a[6]);
        a[7] += o0; a[8] += o1; a[9] += o2;
        a[10] += p0; a[11] += p1; a[12] += p2;
        a[13] = fmaf(o0, p0, a[13]); a[14] = fmaf(o0, p1, a[14]); a[15] = fmaf(o0, p2, a[15]);
        a[16] = fmaf(o1, p0, a[16]); a[17] = fmaf(o1, p1, a[17]); a[18] = fmaf(o1, p2, a[18]);
        a[19] = fmaf(o2, p0, a[19]); a[20] = fmaf(o2, p1, a[20]); a[21] = fmaf(o2, p2, a[21]);
    }
    float inv = __builtin_amdgcn_rcpf(a[0]);
    float cP0 = a[1] * inv, cP1 = a[2] * inv, cP2 = a[3] * inv;
    float cQ0 = a[4] * inv, cQ1 = a[5] * inv, cQ2 = a[6] * inv;
    const float fM = (float)M;
    float S00 = a[13] - cP0 * a[10] - cQ0 * a[7] + fM * cP0 * cQ0;
    float S01 = a[14] - cP0 * a[11] - cQ1 * a[7] + fM * cP0 * cQ1;
    float S02 = a[15] - cP0 * a[12] - cQ2 * a[7] + fM * cP0 * cQ2;
    float S10 = a[16] - cP1 * a[10] - cQ0 * a[8] + fM * cP1 * cQ0;
    float S11 = a[17] - cP1 * a[11] - cQ1 * a[8] + fM * cP1 * cQ1;
    float S12 = a[18] - cP1 * a[12] - cQ2 * a[8] + fM * cP1 * cQ2;
    float S20 = a[19] - cP2 * a[10] - cQ0 * a[9] + fM * cP2 * cQ0;
    float S21 = a[20] - cP2 * a[11] - cQ1 * a[9] + fM * cP2 * cQ1;
    float S22 = a[21] - cP2 * a[12] - cQ2 * a[9] + fM * cP2 * cQ2;
    float Rr[9], tr[3];
    horn_solve(S00, S01, S02, S10, S11, S12, S20, S21, S22,
               cP0, cP1, cP2, cQ0, cQ1, cQ2, Rr, tr);
    float* Rout = out + (size_t)tid * 9;
#pragma unroll
    for (int n = 0; n < 9; ++n) Rout[n] = Rr[n];
    float* tout = out + (size_t)bj_total * 9 + (size_t)tid * 3;
    tout[0] = tr[0]; tout[1] = tr[1]; tout[2] = tr[2];
}

extern "C" void kernel_launch(void* const* d_in, const int* in_sizes, int n_in,
                              void* d_out, int out_size, void* d_ws, size_t ws_size,
                              hipStream_t stream) {
    const float* points = (const float*)d_in[0];
    const float* weight = (const float*)d_in[1];
    const float* offset = (const float*)d_in[2];
    float* out = (float*)d_out;

    int B = in_sizes[0] / (M * 3);
    int bj_total = B * J;
    int q4_total = B * NQ;

    size_t need = (size_t)bj_total * 16 * sizeof(float);   // 6.3 MB at B=4096
    if (ws_size >= need) {
        int grid1 = (q4_total + QPB - 1) / QPB;            // 768
        accum_kernel<<<grid1, 256, 0, stream>>>(points, weight, offset, (float*)d_ws,
                                                q4_total, bj_total);
        solve_kernel<<<(bj_total + 255) / 256, 256, 0, stream>>>((const float*)d_ws, out, bj_total);
    } else {
        fused_kernel<<<(bj_total + 255) / 256, 256, 0, stream>>>(points, weight, offset, out, bj_total);
    }
}

// Round 8
// 150.968 us; speedup vs baseline: 1.0367x; 1.0367x over previous
//
#include <hip/hip_runtime.h>

// SVD_Solver: weighted Kabsch per (batch, joint).  B=4096, M=64, J=24.
// Round 8: minimize distinct-cache-lines-per-wave-instruction (theory: TA/TD
// line processing, not instr count / occupancy / VALU, bound R1-R7 at ~45-60us).
//   accum: 1 block/batch. Stage LINEARLY (coalesced f4 global -> linear
//   ds_write_b128, zero scatter). Accumulate from LDS, t=(j*8+k) k-minor with
//   per-k iteration stagger (<=2-way bank conflicts = free). k-reduction via
//   __shfl_xor(1/2/4) in-register. One barrier. 16-float records -> d_ws.
//   solve: R7-proven Horn-quaternion Jacobi, 1 thread/solve.

constexpr int M = 64;
constexpr int J = 24;
constexpr int NACC = 22;          // W, Wo[3], Wp[3], To[3], Tp[3], Sraw[9]

// LDS float layout (linear, unpadded): w[1536] | o[4608] | p[192] = 6336
constexpr int LW = 0;
constexpr int LO = 1536;
constexpr int LP = 6144;
constexpr int LTOT = 6336;        // 25344 B -> 6 blocks/CU

__global__ __launch_bounds__(256) void accum_kernel(
    const float* __restrict__ points,   // (B, 64, 3)
    const float* __restrict__ weight,   // (B, 64, 24)
    const float* __restrict__ offset,   // (B, 64, 24, 3)
    float* __restrict__ ws,             // AoS: 16 floats per solve
    int bj_total)
{
    __shared__ float smem[LTOT];
    const int t = threadIdx.x;
    const int b = blockIdx.x;

    // ---- stage: pure linear stream, both sides coalesced, no index math ----
    float4* s4 = (float4*)smem;
    const float4* wg4 = (const float4*)(weight + (size_t)b * (M * J));       // 384 f4
    const float4* og4 = (const float4*)(offset + (size_t)b * (M * J * 3));   // 1152 f4
    const float4* pg4 = (const float4*)(points + (size_t)b * (M * 3));       // 48 f4
#pragma unroll
    for (int i = 0; i < 2; ++i) {
        int idx = t + i * 256;
        if (idx < 384) s4[LW / 4 + idx] = wg4[idx];
    }
#pragma unroll
    for (int i = 0; i < 5; ++i) {
        int idx = t + i * 256;
        if (idx < 1152) s4[LO / 4 + idx] = og4[idx];
    }
    if (t < 48) s4[LP / 4 + t] = pg4[t];

    __syncthreads();

    // ---- accumulate: 192 threads, thread (j,k) sums m = k*8 + i', k-minor ----
    if (t >= 192) return;
    const int j = t >> 3;           // 0..23
    const int k = t & 7;            // lane bits 0..2 -> __shfl_xor(1/2/4) reduces k

    float acc[NACC];
#pragma unroll
    for (int n = 0; n < NACC; ++n) acc[n] = 0.0f;

#pragma unroll
    for (int ii = 0; ii < M / 8; ++ii) {
        const int i = (ii + k) & 7;          // stagger: k-groups hit distinct banks
        const int m = k * 8 + i;
        float w  = smem[LW + m * 24 + j];
        float o0 = smem[LO + m * 72 + j * 3 + 0];
        float o1 = smem[LO + m * 72 + j * 3 + 1];
        float o2 = smem[LO + m * 72 + j * 3 + 2];
        float p0 = smem[LP + m * 3 + 0];
        float p1 = smem[LP + m * 3 + 1];
        float p2 = smem[LP + m * 3 + 2];
        acc[0] += w;
        acc[1] = fmaf(w, o0, acc[1]);  acc[2] = fmaf(w, o1, acc[2]);  acc[3] = fmaf(w, o2, acc[3]);
        acc[4] = fmaf(w, p0, acc[4]);  acc[5] = fmaf(w, p1, acc[5]);  acc[6] = fmaf(w, p2, acc[6]);
        acc[7] += o0; acc[8] += o1; acc[9] += o2;
        acc[10] += p0; acc[11] += p1; acc[12] += p2;
        acc[13] = fmaf(o0, p0, acc[13]); acc[14] = fmaf(o0, p1, acc[14]); acc[15] = fmaf(o0, p2, acc[15]);
        acc[16] = fmaf(o1, p0, acc[16]); acc[17] = fmaf(o1, p1, acc[17]); acc[18] = fmaf(o1, p2, acc[18]);
        acc[19] = fmaf(o2, p0, acc[19]); acc[20] = fmaf(o2, p1, acc[20]); acc[21] = fmaf(o2, p2, acc[21]);
    }

    // in-register k-reduction (k = lane bits 0..2)
#pragma unroll
    for (int n = 0; n < NACC; ++n) {
        float v = acc[n];
        v += __shfl_xor(v, 1);
        v += __shfl_xor(v, 2);
        v += __shfl_xor(v, 4);
        acc[n] = v;
    }

    if (k != 0) return;

    const float inv = __builtin_amdgcn_rcpf(acc[0]);
    const float cP0 = acc[1] * inv, cP1 = acc[2] * inv, cP2 = acc[3] * inv;
    const float cQ0 = acc[4] * inv, cQ1 = acc[5] * inv, cQ2 = acc[6] * inv;
    const float To0 = acc[7], To1 = acc[8], To2 = acc[9];
    const float Tp0 = acc[10], Tp1 = acc[11], Tp2 = acc[12];
    const float fM = (float)M;
    float4 f0, f1, f2, f3;
    f0.x = acc[13] - cP0 * Tp0 - cQ0 * To0 + fM * cP0 * cQ0;   // S00
    f0.y = acc[14] - cP0 * Tp1 - cQ1 * To0 + fM * cP0 * cQ1;   // S01
    f0.z = acc[15] - cP0 * Tp2 - cQ2 * To0 + fM * cP0 * cQ2;   // S02
    f0.w = acc[16] - cP1 * Tp0 - cQ0 * To1 + fM * cP1 * cQ0;   // S10
    f1.x = acc[17] - cP1 * Tp1 - cQ1 * To1 + fM * cP1 * cQ1;   // S11
    f1.y = acc[18] - cP1 * Tp2 - cQ2 * To1 + fM * cP1 * cQ2;   // S12
    f1.z = acc[19] - cP2 * Tp0 - cQ0 * To2 + fM * cP2 * cQ0;   // S20
    f1.w = acc[20] - cP2 * Tp1 - cQ1 * To2 + fM * cP2 * cQ1;   // S21
    f2.x = acc[21] - cP2 * Tp2 - cQ2 * To2 + fM * cP2 * cQ2;   // S22
    f2.y = cP0; f2.z = cP1; f2.w = cP2;
    f3.x = cQ0; f3.y = cQ1; f3.z = cQ2; f3.w = 0.0f;

    const int bj = b * J + j;
    float4* dst = (float4*)(ws + (size_t)bj * 16);
    dst[0] = f0; dst[1] = f1; dst[2] = f2; dst[3] = f3;
}

// ---- fast Jacobi rotation: single-instruction rcp/rsq/sqrt ----
template<int P, int Q>
__device__ __forceinline__ void jrot(float A[4][4], float V[4][4]) {
    float apq = A[P][Q];
    float theta = (A[Q][Q] - A[P][P]) * __builtin_amdgcn_rcpf(2.0f * apq);
    float t = __builtin_amdgcn_rcpf(fabsf(theta) + __builtin_amdgcn_sqrtf(fmaf(theta, theta, 1.0f)));
    t = (theta < 0.0f) ? -t : t;
    t = (apq == 0.0f) ? 0.0f : t;            // kills inf/NaN from rcp(0)
    float c = __builtin_amdgcn_rsqf(fmaf(t, t, 1.0f));
    float s = t * c;
#pragma unroll
    for (int k = 0; k < 4; ++k) {
        float akp = A[k][P], akq = A[k][Q];
        A[k][P] = c * akp - s * akq;
        A[k][Q] = s * akp + c * akq;
    }
#pragma unroll
    for (int k = 0; k < 4; ++k) {
        float apk = A[P][k], aqk = A[Q][k];
        A[P][k] = c * apk - s * aqk;
        A[Q][k] = s * apk + c * aqk;
        float vkp = V[k][P], vkq = V[k][Q];
        V[k][P] = c * vkp - s * vkq;
        V[k][Q] = s * vkp + c * vkq;
    }
}

__device__ __forceinline__ void horn_solve(
    float S00, float S01, float S02, float S10, float S11, float S12,
    float S20, float S21, float S22,
    float cP0, float cP1, float cP2, float cQ0, float cQ1, float cQ2,
    float* __restrict__ Rout, float* __restrict__ tout)
{
    float A[4][4], V[4][4];
    A[0][0] = S00 + S11 + S22;
    A[0][1] = A[1][0] = S12 - S21;
    A[0][2] = A[2][0] = S20 - S02;
    A[0][3] = A[3][0] = S01 - S10;
    A[1][1] = S00 - S11 - S22;
    A[1][2] = A[2][1] = S01 + S10;
    A[1][3] = A[3][1] = S02 + S20;
    A[2][2] = -S00 + S11 - S22;
    A[2][3] = A[3][2] = S12 + S21;
    A[3][3] = -S00 - S11 + S22;
#pragma unroll
    for (int r = 0; r < 4; ++r)
#pragma unroll
        for (int c = 0; c < 4; ++c)
            V[r][c] = (r == c) ? 1.0f : 0.0f;

#pragma unroll 1
    for (int sweep = 0; sweep < 6; ++sweep) {
        jrot<0, 1>(A, V); jrot<0, 2>(A, V); jrot<0, 3>(A, V);
        jrot<1, 2>(A, V); jrot<1, 3>(A, V); jrot<2, 3>(A, V);
    }

    float best = A[0][0];
    float qw = V[0][0], qx = V[1][0], qy = V[2][0], qz = V[3][0];
#pragma unroll
    for (int i = 1; i < 4; ++i) {
        bool better = A[i][i] > best;
        best = better ? A[i][i] : best;
        qw = better ? V[0][i] : qw;
        qx = better ? V[1][i] : qx;
        qy = better ? V[2][i] : qy;
        qz = better ? V[3][i] : qz;
    }
    float nrm = __builtin_amdgcn_rsqf(qw * qw + qx * qx + qy * qy + qz * qz);
    qw *= nrm; qx *= nrm; qy *= nrm; qz *= nrm;

    float R00 = 1.f - 2.f * (qy * qy + qz * qz);
    float R01 = 2.f * (qx * qy - qw * qz);
    float R02 = 2.f * (qx * qz + qw * qy);
    float R10 = 2.f * (qx * qy + qw * qz);
    float R11 = 1.f - 2.f * (qx * qx + qz * qz);
    float R12 = 2.f * (qy * qz - qw * qx);
    float R20 = 2.f * (qx * qz - qw * qy);
    float R21 = 2.f * (qy * qz + qw * qx);
    float R22 = 1.f - 2.f * (qx * qx + qy * qy);

    Rout[0] = R00; Rout[1] = R01; Rout[2] = R02;
    Rout[3] = R10; Rout[4] = R11; Rout[5] = R12;
    Rout[6] = R20; Rout[7] = R21; Rout[8] = R22;
    tout[0] = cQ0 - (R00 * cP0 + R01 * cP1 + R02 * cP2);
    tout[1] = cQ1 - (R10 * cP0 + R11 * cP1 + R12 * cP2);
    tout[2] = cQ2 - (R20 * cP0 + R21 * cP1 + R22 * cP2);
}

__global__ __launch_bounds__(256) void solve_kernel(
    const float* __restrict__ ws, float* __restrict__ out, int bj_total)
{
    int tid = blockIdx.x * 256 + threadIdx.x;
    if (tid >= bj_total) return;
    const float4* v = (const float4*)(ws + (size_t)tid * 16);
    float4 f0 = v[0], f1 = v[1], f2 = v[2], f3 = v[3];
    float Rr[9], tr[3];
    horn_solve(f0.x, f0.y, f0.z, f0.w, f1.x, f1.y, f1.z, f1.w, f2.x,
               f2.y, f2.z, f2.w, f3.x, f3.y, f3.z, Rr, tr);
    float* Rout = out + (size_t)tid * 9;
#pragma unroll
    for (int n = 0; n < 9; ++n) Rout[n] = Rr[n];
    float* tout = out + (size_t)bj_total * 9 + (size_t)tid * 3;
    tout[0] = tr[0]; tout[1] = tr[1]; tout[2] = tr[2];
}

// ---- fallback (ws too small): fused one-thread-per-solve ----
__global__ __launch_bounds__(256) void fused_kernel(
    const float* __restrict__ points, const float* __restrict__ weight,
    const float* __restrict__ offset, float* __restrict__ out, int bj_total)
{
    int tid = blockIdx.x * blockDim.x + threadIdx.x;
    if (tid >= bj_total) return;
    int b = tid / J, j = tid - b * J;
    const float* wq = weight + (size_t)b * M * J + j;
    const float* oq = offset + ((size_t)b * M * J + j) * 3;
    const float* pq = points + (size_t)b * M * 3;
    float a[NACC];
#pragma unroll
    for (int n = 0; n < NACC; ++n) a[n] = 0.0f;
#pragma unroll 4
    for (int m = 0; m < M; ++m) {
        float w = wq[m * J];
        float o0 = oq[m * (J * 3) + 0], o1 = oq[m * (J * 3) + 1], o2 = oq[m * (J * 3) + 2];
        float p0 = pq[m * 3 + 0], p1 = pq[m * 3 + 1], p2 = pq[m * 3 + 2];
        a[0] += w;
        a[1] = fmaf(w, o0, a[1]); a[2] = fmaf(w, o1, a[2]); a[3] = fmaf(w, o2, a[3]);
        a[4] = fmaf(w, p0, a[4]); a[5] = fmaf(w, p1, a[5]); a[6] = fmaf(w, p2, a[6]);
        a[7] += o0; a[8] += o1; a[9] += o2;
        a[10] += p0; a[11] += p1; a[12] += p2;
        a[13] = fmaf(o0, p0, a[13]); a[14] = fmaf(o0, p1, a[14]); a[15] = fmaf(o0, p2, a[15]);
        a[16] = fmaf(o1, p0, a[16]); a[17] = fmaf(o1, p1, a[17]); a[18] = fmaf(o1, p2, a[18]);
        a[19] = fmaf(o2, p0, a[19]); a[20] = fmaf(o2, p1, a[20]); a[21] = fmaf(o2, p2, a[21]);
    }
    float inv = __builtin_amdgcn_rcpf(a[0]);
    float cP0 = a[1] * inv, cP1 = a[2] * inv, cP2 = a[3] * inv;
    float cQ0 = a[4] * inv, cQ1 = a[5] * inv, cQ2 = a[6] * inv;
    const float fM = (float)M;
    float S00 = a[13] - cP0 * a[10] - cQ0 * a[7] + fM * cP0 * cQ0;
    float S01 = a[14] - cP0 * a[11] - cQ1 * a[7] + fM * cP0 * cQ1;
    float S02 = a[15] - cP0 * a[12] - cQ2 * a[7] + fM * cP0 * cQ2;
    float S10 = a[16] - cP1 * a[10] - cQ0 * a[8] + fM * cP1 * cQ0;
    float S11 = a[17] - cP1 * a[11] - cQ1 * a[8] + fM * cP1 * cQ1;
    float S12 = a[18] - cP1 * a[12] - cQ2 * a[8] + fM * cP1 * cQ2;
    float S20 = a[19] - cP2 * a[10] - cQ0 * a[9] + fM * cP2 * cQ0;
    float S21 = a[20] - cP2 * a[11] - cQ1 * a[9] + fM * cP2 * cQ1;
    float S22 = a[21] - cP2 * a[12] - cQ2 * a[9] + fM * cP2 * cQ2;
    float Rr[9], tr[3];
    horn_solve(S00, S01, S02, S10, S11, S12, S20, S21, S22,
               cP0, cP1, cP2, cQ0, cQ1, cQ2, Rr, tr);
    float* Rout = out + (size_t)tid * 9;
#pragma unroll
    for (int n = 0; n < 9; ++n) Rout[n] = Rr[n];
    float* tout = out + (size_t)bj_total * 9 + (size_t)tid * 3;
    tout[0] = tr[0]; tout[1] = tr[1]; tout[2] = tr[2];
}

extern "C" void kernel_launch(void* const* d_in, const int* in_sizes, int n_in,
                              void* d_out, int out_size, void* d_ws, size_t ws_size,
                              hipStream_t stream) {
    const float* points = (const float*)d_in[0];
    const float* weight = (const float*)d_in[1];
    const float* offset = (const float*)d_in[2];
    float* out = (float*)d_out;

    int B = in_sizes[0] / (M * 3);
    int bj_total = B * J;

    size_t need = (size_t)bj_total * 16 * sizeof(float);   // 6.3 MB at B=4096
    if (ws_size >= need) {
        accum_kernel<<<B, 256, 0, stream>>>(points, weight, offset, (float*)d_ws, bj_total);
        solve_kernel<<<(bj_total + 255) / 256, 256, 0, stream>>>((const float*)d_ws, out, bj_total);
    } else {
        fused_kernel<<<(bj_total + 255) / 256, 256, 0, stream>>>(points, weight, offset, out, bj_total);
    }
}

// Round 9
// 149.298 us; speedup vs baseline: 1.0482x; 1.0112x over previous
//
#include <hip/hip_runtime.h>

// SVD_Solver: weighted Kabsch per (batch, joint).  B=4096, M=64, J=24.
// Round 9: R8 compute structure + ASYNC staging.
//   accum: 4 batches/block, 2-deep LDS ring. Stage batch g+1 via
//   __builtin_amdgcn_global_load_lds (16B, linear, no VGPR round-trip) while
//   computing batch g; the next barrier's vmcnt drain lands a full compute
//   phase after issue -> load latency hidden. Compute: 192 thr (j*8+k),
//   k-stagger LDS reads, __shfl_xor(1/2/4) k-reduction, 16-float records.
//   solve: proven Horn-quaternion Jacobi, 1 thread/solve.

constexpr int M = 64;
constexpr int J = 24;
constexpr int NACC = 22;          // W, Wo[3], Wp[3], To[3], Tp[3], Sraw[9]

// Per-buffer LDS float layout (linear): w[1536] | o[4608] | p[192]
constexpr int LW = 0;
constexpr int LO = 1536;
constexpr int LP = 6144;
constexpr int LTOT = 6336;        // floats; 2 buffers = 50688 B -> 3 blocks/CU
constexpr int GPB = 4;            // batches per block

// Async global->LDS: one 1KB wave-chunk (lane i -> lds_base + i*16).
__device__ __forceinline__ void chunk_async(const float* src, float* dst, int lane) {
    __builtin_amdgcn_global_load_lds(
        (const __attribute__((address_space(1))) void*)(src + lane * 4),
        (__attribute__((address_space(3))) void*)dst, 16, 0, 0);
}

// Stage one batch (24x 1KB + 1x 768B) spread over the block's 4 waves.
__device__ __forceinline__ void stage_batch(
    const float* __restrict__ w, const float* __restrict__ o,
    const float* __restrict__ p, float* buf, int wv, int lane)
{
#pragma unroll
    for (int c = wv; c < 25; c += 4) {
        if (c < 6) {
            chunk_async(w + c * 256, buf + LW + c * 256, lane);
        } else if (c < 24) {
            chunk_async(o + (c - 6) * 256, buf + LO + (c - 6) * 256, lane);
        } else if (lane < 48) {       // points: 768 B, exec-masked tail
            chunk_async(p, buf + LP, lane);
        }
    }
}

__global__ __launch_bounds__(256) void accum_kernel(
    const float* __restrict__ points,   // (B, 64, 3)
    const float* __restrict__ weight,   // (B, 64, 24)
    const float* __restrict__ offset,   // (B, 64, 24, 3)
    float* __restrict__ ws,             // AoS: 16 floats per solve
    int B, int bj_total)
{
    __shared__ float smem[2 * LTOT];
    const int t    = threadIdx.x;
    const int lane = t & 63;
    const int wv   = t >> 6;
    const int b0   = blockIdx.x * GPB;

    // prologue: stage batch b0 into buffer 0
    if (b0 < B)
        stage_batch(weight + (size_t)b0 * (M * J), offset + (size_t)b0 * (M * J * 3),
                    points + (size_t)b0 * (M * 3), smem, wv, lane);

    const int j = t >> 3;               // 0..23 (t<192)
    const int k = t & 7;                // lane bits 0..2 -> shfl_xor(1/2/4)

#pragma unroll 1
    for (int g = 0; g < GPB; ++g) {
        __syncthreads();                // vmcnt drain: buf[g&1] landed; buf[g^1] free

        if (g + 1 < GPB && b0 + g + 1 < B) {
            const int bn = b0 + g + 1;  // issue next batch, no wait
            stage_batch(weight + (size_t)bn * (M * J), offset + (size_t)bn * (M * J * 3),
                        points + (size_t)bn * (M * 3), smem + ((g + 1) & 1) * LTOT, wv, lane);
        }

        if (t < 192 && b0 + g < B) {
            const float* buf = smem + (g & 1) * LTOT;
            float acc[NACC];
#pragma unroll
            for (int n = 0; n < NACC; ++n) acc[n] = 0.0f;

#pragma unroll
            for (int ii = 0; ii < M / 8; ++ii) {
                const int i = (ii + k) & 7;      // stagger: k-groups hit distinct banks
                const int m = k * 8 + i;
                float w  = buf[LW + m * 24 + j];
                float o0 = buf[LO + m * 72 + j * 3 + 0];
                float o1 = buf[LO + m * 72 + j * 3 + 1];
                float o2 = buf[LO + m * 72 + j * 3 + 2];
                float p0 = buf[LP + m * 3 + 0];
                float p1 = buf[LP + m * 3 + 1];
                float p2 = buf[LP + m * 3 + 2];
                acc[0] += w;
                acc[1] = fmaf(w, o0, acc[1]);  acc[2] = fmaf(w, o1, acc[2]);  acc[3] = fmaf(w, o2, acc[3]);
                acc[4] = fmaf(w, p0, acc[4]);  acc[5] = fmaf(w, p1, acc[5]);  acc[6] = fmaf(w, p2, acc[6]);
                acc[7] += o0; acc[8] += o1; acc[9] += o2;
                acc[10] += p0; acc[11] += p1; acc[12] += p2;
                acc[13] = fmaf(o0, p0, acc[13]); acc[14] = fmaf(o0, p1, acc[14]); acc[15] = fmaf(o0, p2, acc[15]);
                acc[16] = fmaf(o1, p0, acc[16]); acc[17] = fmaf(o1, p1, acc[17]); acc[18] = fmaf(o1, p2, acc[18]);
                acc[19] = fmaf(o2, p0, acc[19]); acc[20] = fmaf(o2, p1, acc[20]); acc[21] = fmaf(o2, p2, acc[21]);
            }

#pragma unroll
            for (int n = 0; n < NACC; ++n) {
                float v = acc[n];
                v += __shfl_xor(v, 1);
                v += __shfl_xor(v, 2);
                v += __shfl_xor(v, 4);
                acc[n] = v;
            }

            if (k == 0) {
                const float inv = __builtin_amdgcn_rcpf(acc[0]);
                const float cP0 = acc[1] * inv, cP1 = acc[2] * inv, cP2 = acc[3] * inv;
                const float cQ0 = acc[4] * inv, cQ1 = acc[5] * inv, cQ2 = acc[6] * inv;
                const float To0 = acc[7], To1 = acc[8], To2 = acc[9];
                const float Tp0 = acc[10], Tp1 = acc[11], Tp2 = acc[12];
                const float fM = (float)M;
                float4 f0, f1, f2, f3;
                f0.x = acc[13] - cP0 * Tp0 - cQ0 * To0 + fM * cP0 * cQ0;
                f0.y = acc[14] - cP0 * Tp1 - cQ1 * To0 + fM * cP0 * cQ1;
                f0.z = acc[15] - cP0 * Tp2 - cQ2 * To0 + fM * cP0 * cQ2;
                f0.w = acc[16] - cP1 * Tp0 - cQ0 * To1 + fM * cP1 * cQ0;
                f1.x = acc[17] - cP1 * Tp1 - cQ1 * To1 + fM * cP1 * cQ1;
                f1.y = acc[18] - cP1 * Tp2 - cQ2 * To1 + fM * cP1 * cQ2;
                f1.z = acc[19] - cP2 * Tp0 - cQ0 * To2 + fM * cP2 * cQ0;
                f1.w = acc[20] - cP2 * Tp1 - cQ1 * To2 + fM * cP2 * cQ1;
                f2.x = acc[21] - cP2 * Tp2 - cQ2 * To2 + fM * cP2 * cQ2;
                f2.y = cP0; f2.z = cP1; f2.w = cP2;
                f3.x = cQ0; f3.y = cQ1; f3.z = cQ2; f3.w = 0.0f;
                const int bj = (b0 + g) * J + j;
                float4* dst = (float4*)(ws + (size_t)bj * 16);
                dst[0] = f0; dst[1] = f1; dst[2] = f2; dst[3] = f3;
            }
        }
    }
}

// ---- fast Jacobi rotation: single-instruction rcp/rsq/sqrt ----
template<int P, int Q>
__device__ __forceinline__ void jrot(float A[4][4], float V[4][4]) {
    float apq = A[P][Q];
    float theta = (A[Q][Q] - A[P][P]) * __builtin_amdgcn_rcpf(2.0f * apq);
    float t = __builtin_amdgcn_rcpf(fabsf(theta) + __builtin_amdgcn_sqrtf(fmaf(theta, theta, 1.0f)));
    t = (theta < 0.0f) ? -t : t;
    t = (apq == 0.0f) ? 0.0f : t;            // kills inf/NaN from rcp(0)
    float c = __builtin_amdgcn_rsqf(fmaf(t, t, 1.0f));
    float s = t * c;
#pragma unroll
    for (int k = 0; k < 4; ++k) {
        float akp = A[k][P], akq = A[k][Q];
        A[k][P] = c * akp - s * akq;
        A[k][Q] = s * akp + c * akq;
    }
#pragma unroll
    for (int k = 0; k < 4; ++k) {
        float apk = A[P][k], aqk = A[Q][k];
        A[P][k] = c * apk - s * aqk;
        A[Q][k] = s * apk + c * aqk;
        float vkp = V[k][P], vkq = V[k][Q];
        V[k][P] = c * vkp - s * vkq;
        V[k][Q] = s * vkp + c * vkq;
    }
}

__device__ __forceinline__ void horn_solve(
    float S00, float S01, float S02, float S10, float S11, float S12,
    float S20, float S21, float S22,
    float cP0, float cP1, float cP2, float cQ0, float cQ1, float cQ2,
    float* __restrict__ Rout, float* __restrict__ tout)
{
    float A[4][4], V[4][4];
    A[0][0] = S00 + S11 + S22;
    A[0][1] = A[1][0] = S12 - S21;
    A[0][2] = A[2][0] = S20 - S02;
    A[0][3] = A[3][0] = S01 - S10;
    A[1][1] = S00 - S11 - S22;
    A[1][2] = A[2][1] = S01 + S10;
    A[1][3] = A[3][1] = S02 + S20;
    A[2][2] = -S00 + S11 - S22;
    A[2][3] = A[3][2] = S12 + S21;
    A[3][3] = -S00 - S11 + S22;
#pragma unroll
    for (int r = 0; r < 4; ++r)
#pragma unroll
        for (int c = 0; c < 4; ++c)
            V[r][c] = (r == c) ? 1.0f : 0.0f;

#pragma unroll 1
    for (int sweep = 0; sweep < 6; ++sweep) {
        jrot<0, 1>(A, V); jrot<0, 2>(A, V); jrot<0, 3>(A, V);
        jrot<1, 2>(A, V); jrot<1, 3>(A, V); jrot<2, 3>(A, V);
    }

    float best = A[0][0];
    float qw = V[0][0], qx = V[1][0], qy = V[2][0], qz = V[3][0];
#pragma unroll
    for (int i = 1; i < 4; ++i) {
        bool better = A[i][i] > best;
        best = better ? A[i][i] : best;
        qw = better ? V[0][i] : qw;
        qx = better ? V[1][i] : qx;
        qy = better ? V[2][i] : qy;
        qz = better ? V[3][i] : qz;
    }
    float nrm = __builtin_amdgcn_rsqf(qw * qw + qx * qx + qy * qy + qz * qz);
    qw *= nrm; qx *= nrm; qy *= nrm; qz *= nrm;

    float R00 = 1.f - 2.f * (qy * qy + qz * qz);
    float R01 = 2.f * (qx * qy - qw * qz);
    float R02 = 2.f * (qx * qz + qw * qy);
    float R10 = 2.f * (qx * qy + qw * qz);
    float R11 = 1.f - 2.f * (qx * qx + qz * qz);
    float R12 = 2.f * (qy * qz - qw * qx);
    float R20 = 2.f * (qx * qz - qw * qy);
    float R21 = 2.f * (qy * qz + qw * qx);
    float R22 = 1.f - 2.f * (qx * qx + qy * qy);

    Rout[0] = R00; Rout[1] = R01; Rout[2] = R02;
    Rout[3] = R10; Rout[4] = R11; Rout[5] = R12;
    Rout[6] = R20; Rout[7] = R21; Rout[8] = R22;
    tout[0] = cQ0 - (R00 * cP0 + R01 * cP1 + R02 * cP2);
    tout[1] = cQ1 - (R10 * cP0 + R11 * cP1 + R12 * cP2);
    tout[2] = cQ2 - (R20 * cP0 + R21 * cP1 + R22 * cP2);
}

__global__ __launch_bounds__(256) void solve_kernel(
    const float* __restrict__ ws, float* __restrict__ out, int bj_total)
{
    int tid = blockIdx.x * 256 + threadIdx.x;
    if (tid >= bj_total) return;
    const float4* v = (const float4*)(ws + (size_t)tid * 16);
    float4 f0 = v[0], f1 = v[1], f2 = v[2], f3 = v[3];
    float Rr[9], tr[3];
    horn_solve(f0.x, f0.y, f0.z, f0.w, f1.x, f1.y, f1.z, f1.w, f2.x,
               f2.y, f2.z, f2.w, f3.x, f3.y, f3.z, Rr, tr);
    float* Rout = out + (size_t)tid * 9;
#pragma unroll
    for (int n = 0; n < 9; ++n) Rout[n] = Rr[n];
    float* tout = out + (size_t)bj_total * 9 + (size_t)tid * 3;
    tout[0] = tr[0]; tout[1] = tr[1]; tout[2] = tr[2];
}

// ---- fallback (ws too small): fused one-thread-per-solve ----
__global__ __launch_bounds__(256) void fused_kernel(
    const float* __restrict__ points, const float* __restrict__ weight,
    const float* __restrict__ offset, float* __restrict__ out, int bj_total)
{
    int tid = blockIdx.x * blockDim.x + threadIdx.x;
    if (tid >= bj_total) return;
    int b = tid / J, j = tid - b * J;
    const float* wq = weight + (size_t)b * M * J + j;
    const float* oq = offset + ((size_t)b * M * J + j) * 3;
    const float* pq = points + (size_t)b * M * 3;
    float a[NACC];
#pragma unroll
    for (int n = 0; n < NACC; ++n) a[n] = 0.0f;
#pragma unroll 4
    for (int m = 0; m < M; ++m) {
        float w = wq[m * J];
        float o0 = oq[m * (J * 3) + 0], o1 = oq[m * (J * 3) + 1], o2 = oq[m * (J * 3) + 2];
        float p0 = pq[m * 3 + 0], p1 = pq[m * 3 + 1], p2 = pq[m * 3 + 2];
        a[0] += w;
        a[1] = fmaf(w, o0, a[1]); a[2] = fmaf(w, o1, a[2]); a[3] = fmaf(w, o2, a[3]);
        a[4] = fmaf(w, p0, a[4]); a[5] = fmaf(w, p1, a[5]); a[6] = fmaf(w, p2, a[6]);
        a[7] += o0; a[8] += o1; a[9] += o2;
        a[10] += p0; a[11] += p1; a[12] += p2;
        a[13] = fmaf(o0, p0, a[13]); a[14] = fmaf(o0, p1, a[14]); a[15] = fmaf(o0, p2, a[15]);
        a[16] = fmaf(o1, p0, a[16]); a[17] = fmaf(o1, p1, a[17]); a[18] = fmaf(o1, p2, a[18]);
        a[19] = fmaf(o2, p0, a[19]); a[20] = fmaf(o2, p1, a[20]); a[21] = fmaf(o2, p2, a[21]);
    }
    float inv = __builtin_amdgcn_rcpf(a[0]);
    float cP0 = a[1] * inv, cP1 = a[2] * inv, cP2 = a[3] * inv;
    float cQ0 = a[4] * inv, cQ1 = a[5] * inv, cQ2 = a[6] * inv;
    const float fM = (float)M;
    float S00 = a[13] - cP0 * a[10] - cQ0 * a[7] + fM * cP0 * cQ0;
    float S01 = a[14] - cP0 * a[11] - cQ1 * a[7] + fM * cP0 * cQ1;
    float S02 = a[15] - cP0 * a[12] - cQ2 * a[7] + fM * cP0 * cQ2;
    float S10 = a[16] - cP1 * a[10] - cQ0 * a[8] + fM * cP1 * cQ0;
    float S11 = a[17] - cP1 * a[11] - cQ1 * a[8] + fM * cP1 * cQ1;
    float S12 = a[18] - cP1 * a[12] - cQ2 * a[8] + fM * cP1 * cQ2;
    float S20 = a[19] - cP2 * a[10] - cQ0 * a[9] + fM * cP2 * cQ0;
    float S21 = a[20] - cP2 * a[11] - cQ1 * a[9] + fM * cP2 * cQ1;
    float S22 = a[21] - cP2 * a[12] - cQ2 * a[9] + fM * cP2 * cQ2;
    float Rr[9], tr[3];
    horn_solve(S00, S01, S02, S10, S11, S12, S20, S21, S22,
               cP0, cP1, cP2, cQ0, cQ1, cQ2, Rr, tr);
    float* Rout = out + (size_t)tid * 9;
#pragma unroll
    for (int n = 0; n < 9; ++n) Rout[n] = Rr[n];
    float* tout = out + (size_t)bj_total * 9 + (size_t)tid * 3;
    tout[0] = tr[0]; tout[1] = tr[1]; tout[2] = tr[2];
}

extern "C" void kernel_launch(void* const* d_in, const int* in_sizes, int n_in,
                              void* d_out, int out_size, void* d_ws, size_t ws_size,
                              hipStream_t stream) {
    const float* points = (const float*)d_in[0];
    const float* weight = (const float*)d_in[1];
    const float* offset = (const float*)d_in[2];
    float* out = (float*)d_out;

    int B = in_sizes[0] / (M * 3);
    int bj_total = B * J;

    size_t need = (size_t)bj_total * 16 * sizeof(float);   // 6.3 MB at B=4096
    if (ws_size >= need) {
        int grid1 = (B + GPB - 1) / GPB;                   // 1024
        accum_kernel<<<grid1, 256, 0, stream>>>(points, weight, offset, (float*)d_ws, B, bj_total);
        solve_kernel<<<(bj_total + 255) / 256, 256, 0, stream>>>((const float*)d_ws, out, bj_total);
    } else {
        fused_kernel<<<(bj_total + 255) / 256, 256, 0, stream>>>(points, weight, offset, out, bj_total);
    }
}